// Round 1
// baseline (92.983 us; speedup 1.0000x reference)
//
#include <hip/hip_runtime.h>

// PointsRenderer: B=4, N=100000, F=64, S=256, K=8, R=2/256
// out = (B, F+1, S, S) f32: channels 0..63 = composited features, 64 = depth.

#define BB 4
#define NN 100000
#define FF 64
#define SS 256
#define KK 8
#define BN (BB * NN)          // 400000
#define RR_INV 16384.0f       // 1 / (r*r),  r = 2*1.0/256

__global__ __launch_bounds__(256)
void points_render_kernel(const float* __restrict__ features, // [BN][FF]
                          const int*   __restrict__ idx,      // [B][S][S][K] int32
                          const float* __restrict__ zbuf,     // [B][S][S][K]
                          const float* __restrict__ dist,     // [B][S][S][K]
                          float* __restrict__ out)            // [B][FF+1][S][S]
{
    // Block covers 64 consecutive x-pixels of one row (b, y).
    // 4 waves/block; wave w handles 16 pixels. lane = feature index f.
    __shared__ float tile[64][FF + 1];   // [local x][channel], stride 65 -> conflict-free

    const int tid  = threadIdx.x;
    const int wave = tid >> 6;
    const int lane = tid & 63;           // feature index

    const int blk = blockIdx.x;          // 4096 blocks
    const int xb  = blk & 3;
    const int y   = (blk >> 2) & (SS - 1);
    const int b   = blk >> 10;
    const int x0  = xb * 64;

    const long long pixbase = (((long long)b * SS + y) * SS + x0);

    for (int i = 0; i < 16; ++i) {
        const int xl = wave * 16 + i;
        const long long p = pixbase + xl;

        // wave-uniform 16B loads of the per-pixel K=8 attributes
        const float4* d4 = (const float4*)(dist + p * KK);
        const float4* z4 = (const float4*)(zbuf + p * KK);
        const int4*   i4 = (const int4*)(idx  + p * KK);
        float4 da = d4[0], db = d4[1];
        float4 za = z4[0], zb = z4[1];
        int4   ia = i4[0], ib = i4[1];

        float dd[KK] = {da.x, da.y, da.z, da.w, db.x, db.y, db.z, db.w};
        float zz[KK] = {za.x, za.y, za.z, za.w, zb.x, zb.y, zb.z, zb.w};
        int   ii[KK] = {ia.x, ia.y, ia.z, ia.w, ib.x, ib.y, ib.z, ib.w};

        float trans = 1.0f, wsum = 0.0f, depth = 0.0f, acc = 0.0f;
        #pragma unroll
        for (int k = 0; k < KK; ++k) {
            float a  = __expf(-fmaxf(dd[k] * RR_INV, 0.0f));
            float we = fminf(a, 0.99f);
            if (ii[k] < 0) we = 0.0f;           // valid mask
            const float contrib = we * trans;
            trans *= (1.0f - we);
            wsum  += we;
            depth += zz[k] * we;

            int si = ii[k];
            si = si < 0 ? 0 : (si > BN - 1 ? BN - 1 : si);  // safe_idx
            // coalesced 256B gather: lane f reads features[si][f]
            acc += features[(long long)si * FF + lane] * contrib;
        }
        depth /= fmaxf(wsum, 1e-9f);

        tile[xl][lane] = acc;
        if (lane == 0) tile[xl][FF] = depth;
    }

    __syncthreads();

    // Write 64 x 65 floats: each 64-thread group writes one contiguous
    // 256B channel segment out[b][c][y][x0..x0+63].
    float* outb = out + (long long)b * (FF + 1) * SS * SS + (long long)y * SS + x0;
    for (int j = tid; j < 64 * (FF + 1); j += 256) {
        const int c  = j >> 6;
        const int xl = j & 63;
        outb[(long long)c * (SS * SS) + xl] = tile[xl][c];
    }
}

extern "C" void kernel_launch(void* const* d_in, const int* in_sizes, int n_in,
                              void* d_out, int out_size, void* d_ws, size_t ws_size,
                              hipStream_t stream) {
    const float* features = (const float*)d_in[0];
    const int*   idx      = (const int*)d_in[1];
    const float* zbuf     = (const float*)d_in[2];
    const float* dist     = (const float*)d_in[3];
    float* out = (float*)d_out;

    const int nblocks = (BB * SS * SS) / 64;   // 4096
    points_render_kernel<<<dim3(nblocks), dim3(256), 0, stream>>>(
        features, idx, zbuf, dist, out);
}

// Round 2
// 91.454 us; speedup vs baseline: 1.0167x; 1.0167x over previous
//
#include <hip/hip_runtime.h>

// PointsRenderer: B=4, N=100000, F=64, S=256, K=8, R=2/256
// out = (B, F+1, S, S) f32: channels 0..63 = composited features, 64 = depth.

#define BB 4
#define NN 100000
#define FF 64
#define SS 256
#define KK 8
#define BN (BB * NN)          // 400000
#define RR_INV 16384.0f       // 1 / (r*r),  r = 2*1.0/256

__global__ __launch_bounds__(256)
void points_render_kernel(const float* __restrict__ features, // [BN][FF]
                          const int*   __restrict__ idx,      // [B][S][S][K] int32
                          const float* __restrict__ zbuf,     // [B][S][S][K]
                          const float* __restrict__ dist,     // [B][S][S][K]
                          float* __restrict__ out)            // [B][FF+1][S][S]
{
    // Block covers 64 consecutive x-pixels of one row (b, y).
    __shared__ float tile[64][FF + 1];      // [local x][channel], stride 65 (+depth)
    __shared__ float s_contrib[64][KK];     // per-(pixel,k) compositing weight
    __shared__ int   s_off[64][KK];         // pre-scaled gather offset si*FF

    const int tid  = threadIdx.x;
    const int wave = tid >> 6;
    const int lane = tid & 63;              // feature index in phase B

    const int blk = blockIdx.x;             // 4096 blocks
    const int xb  = blk & 3;
    const int y   = (blk >> 2) & (SS - 1);
    const int b   = blk >> 10;
    const int x0  = xb * 64;

    const long long pixbase = (((long long)b * SS + y) * SS + x0);

    // ---- Phase A: lane-parallel compositing weights (lane = pixel) ----
    if (tid < 64) {
        const long long p = pixbase + tid;
        const float4* d4 = (const float4*)(dist + p * KK);
        const float4* z4 = (const float4*)(zbuf + p * KK);
        const int4*   i4 = (const int4*)(idx  + p * KK);
        float4 da = d4[0], db = d4[1];
        float4 za = z4[0], zb = z4[1];
        int4   ia = i4[0], ib = i4[1];

        float dd[KK] = {da.x, da.y, da.z, da.w, db.x, db.y, db.z, db.w};
        float zz[KK] = {za.x, za.y, za.z, za.w, zb.x, zb.y, zb.z, zb.w};
        int   ii[KK] = {ia.x, ia.y, ia.z, ia.w, ib.x, ib.y, ib.z, ib.w};

        float trans = 1.0f, wsum = 0.0f, depth = 0.0f;
        #pragma unroll
        for (int k = 0; k < KK; ++k) {
            float a  = __expf(-fmaxf(dd[k] * RR_INV, 0.0f));
            float we = fminf(a, 0.99f);
            if (ii[k] < 0) we = 0.0f;                 // valid mask
            s_contrib[tid][k] = we * trans;
            trans *= (1.0f - we);
            wsum  += we;
            depth += zz[k] * we;

            int si = ii[k];
            si = si < 0 ? 0 : (si > BN - 1 ? BN - 1 : si);  // safe_idx
            s_off[tid][k] = si * FF;
        }
        tile[tid][FF] = depth / fmaxf(wsum, 1e-9f);
    }
    __syncthreads();

    // ---- Phase B: gather + FMA. Wave w owns pixels [w*16, w*16+16). ----
    const float* fl = features + lane;     // per-lane column base

    #pragma unroll 4
    for (int i = 0; i < 16; ++i) {
        const int xl = wave * 16 + i;
        // wave-uniform LDS broadcasts (no conflicts)
        const float4 c0 = *(const float4*)&s_contrib[xl][0];
        const float4 c1 = *(const float4*)&s_contrib[xl][4];
        const int4   o0 = *(const int4*)&s_off[xl][0];
        const int4   o1 = *(const int4*)&s_off[xl][4];

        // 8 coalesced 256B gathers
        const float g0 = fl[o0.x], g1 = fl[o0.y], g2 = fl[o0.z], g3 = fl[o0.w];
        const float g4 = fl[o1.x], g5 = fl[o1.y], g6 = fl[o1.z], g7 = fl[o1.w];

        tile[xl][lane] = g0*c0.x + g1*c0.y + g2*c0.z + g3*c0.w
                       + g4*c1.x + g5*c1.y + g6*c1.z + g7*c1.w;
    }
    __syncthreads();

    // ---- Write 64 x 65 floats: contiguous 256B channel segments ----
    float* outb = out + (long long)b * (FF + 1) * SS * SS + (long long)y * SS + x0;
    for (int j = tid; j < 64 * (FF + 1); j += 256) {
        const int c  = j >> 6;
        const int xl = j & 63;
        outb[(long long)c * (SS * SS) + xl] = tile[xl][c];
    }
}

extern "C" void kernel_launch(void* const* d_in, const int* in_sizes, int n_in,
                              void* d_out, int out_size, void* d_ws, size_t ws_size,
                              hipStream_t stream) {
    const float* features = (const float*)d_in[0];
    const int*   idx      = (const int*)d_in[1];
    const float* zbuf     = (const float*)d_in[2];
    const float* dist     = (const float*)d_in[3];
    float* out = (float*)d_out;

    const int nblocks = (BB * SS * SS) / 64;   // 4096
    points_render_kernel<<<dim3(nblocks), dim3(256), 0, stream>>>(
        features, idx, zbuf, dist, out);
}